// Round 1
// baseline (256.687 us; speedup 1.0000x reference)
//
#include <hip/hip_runtime.h>
#include <hip/hip_bf16.h>

typedef __attribute__((ext_vector_type(8))) short bf16x8;
typedef __attribute__((ext_vector_type(8))) unsigned short ushort8;
typedef __attribute__((ext_vector_type(4))) float f32x4;

__device__ __forceinline__ unsigned short f2bf(float f) {
  union { float f; unsigned int u; } v; v.f = f;
  unsigned int u = v.u;
  unsigned int r = (u + 0x7fffu + ((u >> 16) & 1u)) >> 16;
  return (unsigned short)r;
}

// ---------------- fp32 -> bf16 cast (vectorized) ----------------
__global__ void cast_kernel(const float* __restrict__ in, unsigned short* __restrict__ out, int n4) {
  int i = blockIdx.x * 256 + threadIdx.x;
  if (i < n4) {
    const float4 v = reinterpret_cast<const float4*>(in)[i];
    ushort4 o;
    o.x = f2bf(v.x); o.y = f2bf(v.y); o.z = f2bf(v.z); o.w = f2bf(v.w);
    reinterpret_cast<ushort4*>(out)[i] = o;
  }
}

// ---------------- C[M][N] = A[M][K] * B[N][K]^T, bf16 in, fp32 acc ----------------
// 128x128 tile, BK=32, 4 waves each computing 64x64 (4x4 fragments of 16x16x32).
template<bool OUT_BF16>
__global__ __launch_bounds__(256) void gemm_bt(const unsigned short* __restrict__ A,
                                               const unsigned short* __restrict__ B,
                                               void* __restrict__ Cv,
                                               int M, int N, int K) {
  constexpr int BM = 128, BN = 128, BK = 32;
  __shared__ alignas(16) unsigned short As[BM * BK];
  __shared__ alignas(16) unsigned short Bs[BN * BK];
  const int tid = threadIdx.x;
  const int l  = tid & 63;
  const int w  = tid >> 6;
  const int wr = w >> 1, wc = w & 1;
  const int lr = l & 15, lg = l >> 4;
  const long tile_m = (long)blockIdx.x * BM;
  const long tile_n = (long)blockIdx.y * BN;

  const int c0 = tid, c1 = tid + 256;   // 16B-chunk ids; row = c>>2, col8 = (c&3)*8
  const unsigned short* pa0 = A + (tile_m + (c0 >> 2)) * (long)K + (c0 & 3) * 8;
  const unsigned short* pa1 = A + (tile_m + (c1 >> 2)) * (long)K + (c1 & 3) * 8;
  const unsigned short* pb0 = B + (tile_n + (c0 >> 2)) * (long)K + (c0 & 3) * 8;
  const unsigned short* pb1 = B + (tile_n + (c1 >> 2)) * (long)K + (c1 & 3) * 8;

  f32x4 acc[4][4] = {};

  for (int k0 = 0; k0 < K; k0 += BK) {
    ushort8 a0 = *reinterpret_cast<const ushort8*>(pa0 + k0);
    ushort8 a1 = *reinterpret_cast<const ushort8*>(pa1 + k0);
    ushort8 b0 = *reinterpret_cast<const ushort8*>(pb0 + k0);
    ushort8 b1 = *reinterpret_cast<const ushort8*>(pb1 + k0);
    __syncthreads();
    *reinterpret_cast<ushort8*>(As + c0 * 8) = a0;
    *reinterpret_cast<ushort8*>(As + c1 * 8) = a1;
    *reinterpret_cast<ushort8*>(Bs + c0 * 8) = b0;
    *reinterpret_cast<ushort8*>(Bs + c1 * 8) = b1;
    __syncthreads();
    bf16x8 af[4], bfr[4];
#pragma unroll
    for (int m = 0; m < 4; ++m)
      af[m] = *reinterpret_cast<const bf16x8*>(As + (wr * 64 + m * 16 + lr) * BK + lg * 8);
#pragma unroll
    for (int n = 0; n < 4; ++n)
      bfr[n] = *reinterpret_cast<const bf16x8*>(Bs + (wc * 64 + n * 16 + lr) * BK + lg * 8);
#pragma unroll
    for (int m = 0; m < 4; ++m)
#pragma unroll
      for (int n = 0; n < 4; ++n)
        acc[m][n] = __builtin_amdgcn_mfma_f32_16x16x32_bf16(af[m], bfr[n], acc[m][n], 0, 0, 0);
  }

#pragma unroll
  for (int m = 0; m < 4; ++m) {
#pragma unroll
    for (int n = 0; n < 4; ++n) {
#pragma unroll
      for (int r = 0; r < 4; ++r) {
        long row = tile_m + wr * 64 + m * 16 + lg * 4 + r;
        long col = tile_n + wc * 64 + n * 16 + lr;
        if (OUT_BF16)
          reinterpret_cast<unsigned short*>(Cv)[row * N + col] = f2bf(acc[m][n][r]);
        else
          reinterpret_cast<float*>(Cv)[row * N + col] = acc[m][n][r];
      }
    }
  }
}

// ---------------- causal flash attention ----------------
// grid = (T/64, B*H). Block: 4 waves, wave w owns q-rows [qt*64 + w*16, +16).
// qkv layout: [B*T][3072] bf16 (q at e=h*64, k at 1024+h*64, v at 2048+h*64).
__global__ __launch_bounds__(256) void attn_kernel(const unsigned short* __restrict__ qkv,
                                                   unsigned short* __restrict__ o) {
  constexpr int E = 3072, T = 2048, D = 64;
  __shared__ alignas(16) unsigned short Ks[64 * 64];       // [k-row][d]
  __shared__ alignas(16) unsigned short Vt[64 * 64];       // [d][k-row] (transposed)
  __shared__ alignas(16) unsigned short Ps[4][16 * 64];    // per-wave P tile [qrow][k]
  const int qt = blockIdx.x;
  const int bh = blockIdx.y;
  const int b = bh >> 4, h = bh & 15;
  const int tid = threadIdx.x;
  const int l = tid & 63, w = tid >> 6;
  const int lr = l & 15, lg = l >> 4;

  const unsigned short* Qb = qkv + (size_t)b * T * E + h * D;
  const unsigned short* Kb = Qb + 1024;
  const unsigned short* Vb = Qb + 2048;

  const int q0 = qt * 64 + w * 16;
  bf16x8 aq[2];
#pragma unroll
  for (int dc = 0; dc < 2; ++dc)
    aq[dc] = *reinterpret_cast<const bf16x8*>(Qb + (size_t)(q0 + lr) * E + dc * 32 + lg * 8);

  float mr[4], lsum[4];
  f32x4 accO[4] = {};
#pragma unroll
  for (int r = 0; r < 4; ++r) { mr[r] = -1e30f; lsum[r] = 0.f; }

  const int ntiles = qt + 1;
  for (int t = 0; t < ntiles; ++t) {
    __syncthreads();
    // stage K row-major and V transposed
#pragma unroll
    for (int i = 0; i < 2; ++i) {
      int c = i * 256 + tid;            // 512 chunks of 8 elems; row = c>>3, col8 = (c&7)*8
      int kr = c >> 3, cc = (c & 7) * 8;
      *reinterpret_cast<ushort8*>(Ks + kr * 64 + cc) =
          *reinterpret_cast<const ushort8*>(Kb + (size_t)(t * 64 + kr) * E + cc);
      ushort8 v = *reinterpret_cast<const ushort8*>(Vb + (size_t)(t * 64 + kr) * E + cc);
#pragma unroll
      for (int j = 0; j < 8; ++j) Vt[(cc + j) * 64 + kr] = v[j];
    }
    __syncthreads();

    // S = Q K^T  (A = Q[16][64], B = K^T; both K-contiguous reads)
    f32x4 s[4] = {};
#pragma unroll
    for (int n = 0; n < 4; ++n) {
#pragma unroll
      for (int dc = 0; dc < 2; ++dc) {
        bf16x8 bk = *reinterpret_cast<const bf16x8*>(Ks + (n * 16 + lr) * 64 + dc * 32 + lg * 8);
        s[n] = __builtin_amdgcn_mfma_f32_16x16x32_bf16(aq[dc], bk, s[n], 0, 0, 0);
      }
    }

    // scale + causal mask + row max (row = (lg*4+r), cols distributed over 16 lanes)
    float pm[4];
#pragma unroll
    for (int r = 0; r < 4; ++r) pm[r] = -1e30f;
    const bool diag = (t == qt);
#pragma unroll
    for (int n = 0; n < 4; ++n) {
#pragma unroll
      for (int r = 0; r < 4; ++r) {
        float v = s[n][r] * 0.125f;
        if (diag) {
          int col = n * 16 + lr;            // local col within kv tile
          int row = w * 16 + lg * 4 + r;    // local row within q tile (t == qt)
          if (col > row) v = -1e30f;
        }
        s[n][r] = v;
        pm[r] = fmaxf(pm[r], v);
      }
    }
#pragma unroll
    for (int r = 0; r < 4; ++r) {
#pragma unroll
      for (int off = 1; off < 16; off <<= 1)
        pm[r] = fmaxf(pm[r], __shfl_xor(pm[r], off));
      float mn = fmaxf(mr[r], pm[r]);
      float al = __expf(mr[r] - mn);
      mr[r] = mn;
      lsum[r] *= al;
#pragma unroll
      for (int dn = 0; dn < 4; ++dn) accO[dn][r] *= al;
    }

    // P = exp(S - m); partial (per-lane) row sums; P -> LDS as bf16
#pragma unroll
    for (int n = 0; n < 4; ++n) {
#pragma unroll
      for (int r = 0; r < 4; ++r) {
        float p = __expf(s[n][r] - mr[r]);
        lsum[r] += p;
        Ps[w][(lg * 4 + r) * 64 + n * 16 + lr] = f2bf(p);
      }
    }
    __syncthreads();  // conservative: make P visible before A-frag reads

    // O += P V   (A = P[16][64] from LDS, B = V from transposed LDS)
#pragma unroll
    for (int kk = 0; kk < 2; ++kk) {
      bf16x8 ap = *reinterpret_cast<const bf16x8*>(Ps[w] + lr * 64 + kk * 32 + lg * 8);
#pragma unroll
      for (int dn = 0; dn < 4; ++dn) {
        bf16x8 bv = *reinterpret_cast<const bf16x8*>(Vt + (dn * 16 + lr) * 64 + kk * 32 + lg * 8);
        accO[dn] = __builtin_amdgcn_mfma_f32_16x16x32_bf16(ap, bv, accO[dn], 0, 0, 0);
      }
    }
  }

  // finalize: reduce row-sums across the 16-lane group, normalize, store
#pragma unroll
  for (int r = 0; r < 4; ++r) {
#pragma unroll
    for (int off = 1; off < 16; off <<= 1)
      lsum[r] += __shfl_xor(lsum[r], off);
    lsum[r] = 1.f / lsum[r];
  }
#pragma unroll
  for (int dn = 0; dn < 4; ++dn) {
#pragma unroll
    for (int r = 0; r < 4; ++r) {
      int row = q0 + lg * 4 + r;
      int col = h * D + dn * 16 + lr;
      o[(size_t)(b * T + row) * 1024 + col] = f2bf(accO[dn][r] * lsum[r]);
    }
  }
}

extern "C" void kernel_launch(void* const* d_in, const int* in_sizes, int n_in,
                              void* d_out, int out_size, void* d_ws, size_t ws_size,
                              hipStream_t stream) {
  const float* x     = (const float*)d_in[0];   // [2,2048,1024]
  const float* w_qkv = (const float*)d_in[1];   // [3072,1024]
  const float* w_out = (const float*)d_in[2];   // [1024,1024]
  float* out = (float*)d_out;                   // [2,2048,1024] fp32

  unsigned short* xb    = (unsigned short*)d_ws;                  // 4096*1024 bf16
  unsigned short* wqkvb = xb    + (size_t)4096 * 1024;            // 3072*1024
  unsigned short* woutb = wqkvb + (size_t)3072 * 1024;            // 1024*1024
  unsigned short* qkv   = woutb + (size_t)1024 * 1024;            // 4096*3072
  unsigned short* attn  = qkv   + (size_t)4096 * 3072;            // 4096*1024
  // total ws use: 24M ushorts = 48 MB

  cast_kernel<<<dim3(1024), 256, 0, stream>>>(x,     xb,    4096 * 1024 / 4);
  cast_kernel<<<dim3(3072), 256, 0, stream>>>(w_qkv, wqkvb, 3072 * 1024 / 4);
  cast_kernel<<<dim3(1024), 256, 0, stream>>>(w_out, woutb, 1024 * 1024 / 4);
  // fix grid for x: 4096*1024/4 = 1,048,576 elems -> 4096 blocks
  cast_kernel<<<dim3(4096), 256, 0, stream>>>(x, xb, 4096 * 1024 / 4);

  gemm_bt<true ><<<dim3(32, 24), 256, 0, stream>>>(xb,   wqkvb, (void*)qkv,  4096, 3072, 1024);
  attn_kernel  <<<dim3(32, 32), 256, 0, stream>>>(qkv, attn);
  gemm_bt<false><<<dim3(32,  8), 256, 0, stream>>>(attn, woutb, (void*)out, 4096, 1024, 1024);
}

// Round 2
// 146.521 us; speedup vs baseline: 1.7519x; 1.7519x over previous
//
#include <hip/hip_runtime.h>
#include <hip/hip_bf16.h>

typedef __attribute__((ext_vector_type(8))) short bf16x8;
typedef __attribute__((ext_vector_type(8))) unsigned short ushort8;
typedef __attribute__((ext_vector_type(4))) float f32x4;

typedef const __attribute__((address_space(1))) void gvoid;
typedef __attribute__((address_space(3))) void svoid;

__device__ __forceinline__ unsigned short f2bf(float f) {
  union { float f; unsigned int u; } v; v.f = f;
  unsigned int u = v.u;
  unsigned int r = (u + 0x7fffu + ((u >> 16) & 1u)) >> 16;
  return (unsigned short)r;
}

// ---------------- fp32 -> bf16 cast (vectorized) ----------------
__global__ void cast_kernel(const float* __restrict__ in, unsigned short* __restrict__ out, int n4) {
  int i = blockIdx.x * 256 + threadIdx.x;
  if (i < n4) {
    const float4 v = reinterpret_cast<const float4*>(in)[i];
    ushort4 o;
    o.x = f2bf(v.x); o.y = f2bf(v.y); o.z = f2bf(v.z); o.w = f2bf(v.w);
    reinterpret_cast<ushort4*>(out)[i] = o;
  }
}

// ---------------- C[M][N] = A[M][K] * B[N][K]^T, bf16 in, fp32 acc ----------------
// 128x128 tile, BK=32, 4 waves; staging via global_load_lds width=16 (m97 pattern).
template<bool OUT_BF16>
__global__ __launch_bounds__(256) void gemm_bt(const unsigned short* __restrict__ A,
                                               const unsigned short* __restrict__ B,
                                               void* __restrict__ Cv,
                                               int M, int N, int K) {
  constexpr int BM = 128, BK = 32;
  __shared__ alignas(16) unsigned short As[BM * BK];
  __shared__ alignas(16) unsigned short Bs[BM * BK];
  const int tid = threadIdx.x;
  const int l  = tid & 63;
  const int w  = tid >> 6;
  const int wr = w >> 1, wc = w & 1;
  const int lr = l & 15, lg = l >> 4;
  const long tile_m = (long)blockIdx.x * BM;
  const long tile_n = (long)blockIdx.y * BM;

  const int c0 = tid, c1 = tid + 256;   // 16B-chunk ids; row = c>>2, col8 = (c&3)*8
  const unsigned short* pa0 = A + (tile_m + (c0 >> 2)) * (long)K + (c0 & 3) * 8;
  const unsigned short* pa1 = A + (tile_m + (c1 >> 2)) * (long)K + (c1 & 3) * 8;
  const unsigned short* pb0 = B + (tile_n + (c0 >> 2)) * (long)K + (c0 & 3) * 8;
  const unsigned short* pb1 = B + (tile_n + (c1 >> 2)) * (long)K + (c1 & 3) * 8;
  // wave-uniform LDS destinations (HW writes base + lane*16)
  unsigned short* lA0 = As + (w * 64) * 8;
  unsigned short* lA1 = As + (256 + w * 64) * 8;
  unsigned short* lB0 = Bs + (w * 64) * 8;
  unsigned short* lB1 = Bs + (256 + w * 64) * 8;

  f32x4 acc[4][4] = {};

  for (int k0 = 0; k0 < K; k0 += BK) {
    __syncthreads();
    __builtin_amdgcn_global_load_lds((gvoid*)(pa0 + k0), (svoid*)lA0, 16, 0, 0);
    __builtin_amdgcn_global_load_lds((gvoid*)(pa1 + k0), (svoid*)lA1, 16, 0, 0);
    __builtin_amdgcn_global_load_lds((gvoid*)(pb0 + k0), (svoid*)lB0, 16, 0, 0);
    __builtin_amdgcn_global_load_lds((gvoid*)(pb1 + k0), (svoid*)lB1, 16, 0, 0);
    __syncthreads();
    bf16x8 af[4], bfr[4];
#pragma unroll
    for (int m = 0; m < 4; ++m)
      af[m] = *reinterpret_cast<const bf16x8*>(As + (wr * 64 + m * 16 + lr) * BK + lg * 8);
#pragma unroll
    for (int n = 0; n < 4; ++n)
      bfr[n] = *reinterpret_cast<const bf16x8*>(Bs + (wc * 64 + n * 16 + lr) * BK + lg * 8);
#pragma unroll
    for (int m = 0; m < 4; ++m)
#pragma unroll
      for (int n = 0; n < 4; ++n)
        acc[m][n] = __builtin_amdgcn_mfma_f32_16x16x32_bf16(af[m], bfr[n], acc[m][n], 0, 0, 0);
  }

#pragma unroll
  for (int m = 0; m < 4; ++m)
#pragma unroll
    for (int n = 0; n < 4; ++n)
#pragma unroll
      for (int r = 0; r < 4; ++r) {
        long row = tile_m + wr * 64 + m * 16 + lg * 4 + r;
        long col = tile_n + wc * 64 + n * 16 + lr;
        if (OUT_BF16)
          reinterpret_cast<unsigned short*>(Cv)[row * N + col] = f2bf(acc[m][n][r]);
        else
          reinterpret_cast<float*>(Cv)[row * N + col] = acc[m][n][r];
      }
}

// ---------------- causal flash attention ----------------
// grid = (8, B*H). 8 waves x 16 q-rows = 128 q-rows per q-tile; each block
// processes TWO q-tiles {15-bx, bx} -> exactly 34 KV-tile iterations (balanced).
// All LDS tiles XOR-swizzled: 16B slot s at row r lives at slot s^(r&7).
__global__ __launch_bounds__(512) void attn_kernel(const unsigned short* __restrict__ qkv,
                                                   unsigned short* __restrict__ o) {
  constexpr int E = 3072, T = 2048;
  __shared__ alignas(16) unsigned short Ks[64 * 64];      // [k][d] swizzled
  __shared__ alignas(16) unsigned short Vt[64 * 64];      // [d][k] swizzled (transposed)
  __shared__ alignas(16) unsigned short Ps[8][16 * 64];   // per-wave [q][k] swizzled
  const int tid = threadIdx.x;
  const int l = tid & 63, w = tid >> 6;
  const int lr = l & 15, lg = l >> 4;
  const int bh = blockIdx.y, b = bh >> 4, h = bh & 15;
  const unsigned short* Qb = qkv + (size_t)b * T * E + h * 64;
  const unsigned short* Kb = Qb + 1024;
  const unsigned short* Vb = Qb + 2048;
  const int kr = tid >> 3;          // staging row 0..63
  const int js = tid & 7;           // staging 16B slot 0..7
  unsigned short* PsW = Ps[w];

  for (int seg = 0; seg < 2; ++seg) {
    const int qtb = (seg == 0) ? (15 - (int)blockIdx.x) : (int)blockIdx.x;
    const int qrow = qtb * 128 + w * 16;   // wave's first q-row

    bf16x8 aq[2];
#pragma unroll
    for (int dc = 0; dc < 2; ++dc)
      aq[dc] = *reinterpret_cast<const bf16x8*>(Qb + (size_t)(qrow + lr) * E + dc * 32 + lg * 8);

    float mr[4], ls[4];
    f32x4 accO[4] = {};
#pragma unroll
    for (int r = 0; r < 4; ++r) { mr[r] = -1e30f; ls[r] = 0.f; }

    const int nt = 2 * qtb + 2;
    ushort8 kreg = *reinterpret_cast<const ushort8*>(Kb + (size_t)kr * E + js * 8);
    ushort8 vreg = *reinterpret_cast<const ushort8*>(Vb + (size_t)kr * E + js * 8);

    for (int t = 0; t < nt; ++t) {
      __syncthreads();   // previous tile's compute done; safe to overwrite LDS
      *reinterpret_cast<ushort8*>(Ks + kr * 64 + ((js ^ (kr & 7)) << 3)) = kreg;
#pragma unroll
      for (int e = 0; e < 8; ++e) {
        int d = js * 8 + e;
        Vt[d * 64 + ((((kr >> 3) ^ (d & 7)) << 3) | (kr & 7))] = (unsigned short)vreg[e];
      }
      __syncthreads();   // staging visible to all waves
      if (t + 1 < nt) {  // prefetch next tile; lands during compute
        kreg = *reinterpret_cast<const ushort8*>(Kb + (size_t)((t + 1) * 64 + kr) * E + js * 8);
        vreg = *reinterpret_cast<const ushort8*>(Vb + (size_t)((t + 1) * 64 + kr) * E + js * 8);
      }

      // S = Q K^T
      f32x4 s[4] = {};
#pragma unroll
      for (int n = 0; n < 4; ++n)
#pragma unroll
        for (int dc = 0; dc < 2; ++dc) {
          bf16x8 bk = *reinterpret_cast<const bf16x8*>(
              Ks + (n * 16 + lr) * 64 + (((dc * 4 + lg) ^ (lr & 7)) << 3));
          s[n] = __builtin_amdgcn_mfma_f32_16x16x32_bf16(aq[dc], bk, s[n], 0, 0, 0);
        }

      // scale + causal mask
      const bool needMask = (t * 64 + 63) > qrow;   // wave-uniform
#pragma unroll
      for (int n = 0; n < 4; ++n) {
        const int gcol = t * 64 + n * 16 + lr;
#pragma unroll
        for (int r = 0; r < 4; ++r) {
          float v = s[n][r] * 0.125f;
          if (needMask && gcol > qrow + lg * 4 + r) v = -1e30f;
          s[n][r] = v;
        }
      }
      // online softmax: row max over 16 lanes, rescale
#pragma unroll
      for (int r = 0; r < 4; ++r) {
        float pm = fmaxf(fmaxf(s[0][r], s[1][r]), fmaxf(s[2][r], s[3][r]));
#pragma unroll
        for (int off = 1; off < 16; off <<= 1)
          pm = fmaxf(pm, __shfl_xor(pm, off));
        float mn = fmaxf(mr[r], pm);
        float al = __expf(mr[r] - mn);
        mr[r] = mn;
        ls[r] *= al;
#pragma unroll
        for (int dn = 0; dn < 4; ++dn) accO[dn][r] *= al;
      }
      // P = exp(S-m) -> per-wave LDS (swizzled)
#pragma unroll
      for (int n = 0; n < 4; ++n)
#pragma unroll
        for (int r = 0; r < 4; ++r) {
          float p = __expf(s[n][r] - mr[r]);
          ls[r] += p;
          int row = lg * 4 + r, col = n * 16 + lr;
          PsW[row * 64 + ((((col >> 3) ^ (row & 7)) << 3) | (col & 7))] = f2bf(p);
        }
      asm volatile("s_waitcnt lgkmcnt(0)" ::: "memory");  // own-wave P writes done
      __builtin_amdgcn_sched_barrier(0);

      // O += P V
#pragma unroll
      for (int kk = 0; kk < 2; ++kk) {
        bf16x8 ap = *reinterpret_cast<const bf16x8*>(
            PsW + lr * 64 + (((kk * 4 + lg) ^ (lr & 7)) << 3));
#pragma unroll
        for (int dn = 0; dn < 4; ++dn) {
          bf16x8 bv = *reinterpret_cast<const bf16x8*>(
              Vt + (dn * 16 + lr) * 64 + (((kk * 4 + lg) ^ (lr & 7)) << 3));
          accO[dn] = __builtin_amdgcn_mfma_f32_16x16x32_bf16(ap, bv, accO[dn], 0, 0, 0);
        }
      }
    } // t

#pragma unroll
    for (int r = 0; r < 4; ++r) {
#pragma unroll
      for (int off = 1; off < 16; off <<= 1)
        ls[r] += __shfl_xor(ls[r], off);
      ls[r] = 1.f / ls[r];
    }
#pragma unroll
    for (int dn = 0; dn < 4; ++dn)
#pragma unroll
      for (int r = 0; r < 4; ++r) {
        int row = qrow + lg * 4 + r;
        int col = h * 64 + dn * 16 + lr;
        o[(size_t)(b * T + row) * 1024 + col] = f2bf(accO[dn][r] * ls[r]);
      }
  } // seg
}

extern "C" void kernel_launch(void* const* d_in, const int* in_sizes, int n_in,
                              void* d_out, int out_size, void* d_ws, size_t ws_size,
                              hipStream_t stream) {
  const float* x     = (const float*)d_in[0];   // [2,2048,1024]
  const float* w_qkv = (const float*)d_in[1];   // [3072,1024]
  const float* w_out = (const float*)d_in[2];   // [1024,1024]
  float* out = (float*)d_out;                   // [2,2048,1024] fp32

  unsigned short* xb    = (unsigned short*)d_ws;                  // 4096*1024
  unsigned short* wqkvb = xb    + (size_t)4096 * 1024;            // 3072*1024
  unsigned short* woutb = wqkvb + (size_t)3072 * 1024;            // 1024*1024
  unsigned short* qkv   = woutb + (size_t)1024 * 1024;            // 4096*3072
  unsigned short* attn  = qkv   + (size_t)4096 * 3072;            // 4096*1024

  cast_kernel<<<dim3(4096), 256, 0, stream>>>(x,     xb,    4096 * 1024 / 4);
  cast_kernel<<<dim3(3072), 256, 0, stream>>>(w_qkv, wqkvb, 3072 * 1024 / 4);
  cast_kernel<<<dim3(1024), 256, 0, stream>>>(w_out, woutb, 1024 * 1024 / 4);

  gemm_bt<true ><<<dim3(32, 24), 256, 0, stream>>>(xb,   wqkvb, (void*)qkv,  4096, 3072, 1024);
  attn_kernel  <<<dim3(8,  32), 512, 0, stream>>>(qkv, attn);
  gemm_bt<false><<<dim3(32,  8), 256, 0, stream>>>(attn, woutb, (void*)out, 4096, 1024, 1024);
}

// Round 3
// 136.054 us; speedup vs baseline: 1.8867x; 1.0769x over previous
//
#include <hip/hip_runtime.h>
#include <hip/hip_bf16.h>

typedef __attribute__((ext_vector_type(8))) short bf16x8;
typedef __attribute__((ext_vector_type(8))) unsigned short ushort8;
typedef __attribute__((ext_vector_type(4))) float f32x4;

typedef const __attribute__((address_space(1))) void gvoid;
typedef __attribute__((address_space(3))) void svoid;

__device__ __forceinline__ unsigned short f2bf(float f) {
  union { float f; unsigned int u; } v; v.f = f;
  unsigned int u = v.u;
  unsigned int r = (u + 0x7fffu + ((u >> 16) & 1u)) >> 16;
  return (unsigned short)r;
}

// ---------------- fp32 -> bf16 cast (vectorized) ----------------
__global__ void cast_kernel(const float* __restrict__ in, unsigned short* __restrict__ out, int n4) {
  int i = blockIdx.x * 256 + threadIdx.x;
  if (i < n4) {
    const float4 v = reinterpret_cast<const float4*>(in)[i];
    ushort4 o;
    o.x = f2bf(v.x); o.y = f2bf(v.y); o.z = f2bf(v.z); o.w = f2bf(v.w);
    reinterpret_cast<ushort4*>(out)[i] = o;
  }
}

// ---------------- C[M][N] = A[M][K] * B[N][K]^T, bf16 in, fp32 acc ----------------
// 128x128 tile, BK=32, 4 waves; staging via global_load_lds width=16 (m97 pattern).
template<bool OUT_BF16>
__global__ __launch_bounds__(256) void gemm_bt(const unsigned short* __restrict__ A,
                                               const unsigned short* __restrict__ B,
                                               void* __restrict__ Cv,
                                               int M, int N, int K) {
  constexpr int BM = 128, BK = 32;
  __shared__ alignas(16) unsigned short As[BM * BK];
  __shared__ alignas(16) unsigned short Bs[BM * BK];
  const int tid = threadIdx.x;
  const int l  = tid & 63;
  const int w  = tid >> 6;
  const int wr = w >> 1, wc = w & 1;
  const int lr = l & 15, lg = l >> 4;
  const long tile_m = (long)blockIdx.x * BM;
  const long tile_n = (long)blockIdx.y * BM;

  const int c0 = tid, c1 = tid + 256;   // 16B-chunk ids; row = c>>2, col8 = (c&3)*8
  const unsigned short* pa0 = A + (tile_m + (c0 >> 2)) * (long)K + (c0 & 3) * 8;
  const unsigned short* pa1 = A + (tile_m + (c1 >> 2)) * (long)K + (c1 & 3) * 8;
  const unsigned short* pb0 = B + (tile_n + (c0 >> 2)) * (long)K + (c0 & 3) * 8;
  const unsigned short* pb1 = B + (tile_n + (c1 >> 2)) * (long)K + (c1 & 3) * 8;
  // wave-uniform LDS destinations (HW writes base + lane*16)
  unsigned short* lA0 = As + (w * 64) * 8;
  unsigned short* lA1 = As + (256 + w * 64) * 8;
  unsigned short* lB0 = Bs + (w * 64) * 8;
  unsigned short* lB1 = Bs + (256 + w * 64) * 8;

  f32x4 acc[4][4] = {};

  for (int k0 = 0; k0 < K; k0 += BK) {
    __syncthreads();
    __builtin_amdgcn_global_load_lds((gvoid*)(pa0 + k0), (svoid*)lA0, 16, 0, 0);
    __builtin_amdgcn_global_load_lds((gvoid*)(pa1 + k0), (svoid*)lA1, 16, 0, 0);
    __builtin_amdgcn_global_load_lds((gvoid*)(pb0 + k0), (svoid*)lB0, 16, 0, 0);
    __builtin_amdgcn_global_load_lds((gvoid*)(pb1 + k0), (svoid*)lB1, 16, 0, 0);
    __syncthreads();
    bf16x8 af[4], bfr[4];
#pragma unroll
    for (int m = 0; m < 4; ++m)
      af[m] = *reinterpret_cast<const bf16x8*>(As + (wr * 64 + m * 16 + lr) * BK + lg * 8);
#pragma unroll
    for (int n = 0; n < 4; ++n)
      bfr[n] = *reinterpret_cast<const bf16x8*>(Bs + (wc * 64 + n * 16 + lr) * BK + lg * 8);
#pragma unroll
    for (int m = 0; m < 4; ++m)
#pragma unroll
      for (int n = 0; n < 4; ++n)
        acc[m][n] = __builtin_amdgcn_mfma_f32_16x16x32_bf16(af[m], bfr[n], acc[m][n], 0, 0, 0);
  }

#pragma unroll
  for (int m = 0; m < 4; ++m)
#pragma unroll
    for (int n = 0; n < 4; ++n)
#pragma unroll
      for (int r = 0; r < 4; ++r) {
        long row = tile_m + wr * 64 + m * 16 + lg * 4 + r;
        long col = tile_n + wc * 64 + n * 16 + lr;
        if (OUT_BF16)
          reinterpret_cast<unsigned short*>(Cv)[row * N + col] = f2bf(acc[m][n][r]);
        else
          reinterpret_cast<float*>(Cv)[row * N + col] = acc[m][n][r];
      }
}

// ---------------- causal flash attention ----------------
// grid = 512 blocks, 8 waves. Block i handles ONE 128-row q-tile of one (b,h):
//   half = i>>8, bx = i&15, bh = (i>>4)&15 | half<<4, qtb = half ? 15-bx : bx.
// Under in-order dispatch, blocks i and i+256 (co-resident on a CU) have
// complementary causal work (nt + nt' = 34). 2 blocks/CU target.
// LDS swizzles: K slot^=(row&7); Vt slot^=(d^(d>>3))&7 (conflict-free for both
// the scalar transpose WRITES (d>>3 varies per lane) and the b128 PV reads
// ((d&7) varies per lane)); P slot^=(row&7).
__global__ __launch_bounds__(512, 4) void attn_kernel(const unsigned short* __restrict__ qkv,
                                                      unsigned short* __restrict__ o) {
  constexpr int E = 3072, T = 2048;
  __shared__ alignas(16) unsigned short Ks[64 * 64];      // [k][d]
  __shared__ alignas(16) unsigned short Vt[64 * 64];      // [d][k] transposed
  __shared__ alignas(16) unsigned short Ps[8][16 * 64];   // per-wave [q][k]
  const int tid = threadIdx.x;
  const int l = tid & 63, w = tid >> 6;
  const int lr = l & 15, lg = l >> 4;
  const int id = blockIdx.x;
  const int half = id >> 8, rr = id & 255;
  const int bx = rr & 15;
  const int bh = (rr >> 4) | (half << 4);
  const int qtb = half ? (15 - bx) : bx;
  const int b = bh >> 4, h = bh & 15;
  const unsigned short* Qb = qkv + (size_t)b * T * E + h * 64;
  const unsigned short* Kb = Qb + 1024;
  const unsigned short* Vb = Qb + 2048;
  const int kr = tid >> 3;          // staging row 0..63
  const int js = tid & 7;           // staging 16B slot 0..7
  unsigned short* PsW = Ps[w];

  const int qrow = qtb * 128 + w * 16;   // wave's first q-row

  bf16x8 aq[2];
#pragma unroll
  for (int dc = 0; dc < 2; ++dc)
    aq[dc] = *reinterpret_cast<const bf16x8*>(Qb + (size_t)(qrow + lr) * E + dc * 32 + lg * 8);

  float mr[4], ls[4];
  f32x4 accO[4] = {};
#pragma unroll
  for (int r = 0; r < 4; ++r) { mr[r] = -1e30f; ls[r] = 0.f; }

  const int nt = 2 * qtb + 2;
  ushort8 kreg = *reinterpret_cast<const ushort8*>(Kb + (size_t)kr * E + js * 8);
  ushort8 vreg = *reinterpret_cast<const ushort8*>(Vb + (size_t)kr * E + js * 8);

  for (int t = 0; t < nt; ++t) {
    __syncthreads();   // previous tile's compute done; safe to overwrite LDS
    *reinterpret_cast<ushort8*>(Ks + kr * 64 + ((js ^ (kr & 7)) << 3)) = kreg;
#pragma unroll
    for (int e = 0; e < 8; ++e) {
      int d = js * 8 + e;
      int swz = (d ^ (d >> 3)) & 7;
      Vt[d * 64 + ((((kr >> 3) ^ swz) << 3) | (kr & 7))] = (unsigned short)vreg[e];
    }
    __syncthreads();   // staging visible to all waves
    if (t + 1 < nt) {  // prefetch next tile; lands during compute
      kreg = *reinterpret_cast<const ushort8*>(Kb + (size_t)((t + 1) * 64 + kr) * E + js * 8);
      vreg = *reinterpret_cast<const ushort8*>(Vb + (size_t)((t + 1) * 64 + kr) * E + js * 8);
    }

    // S = Q K^T
    f32x4 s[4] = {};
#pragma unroll
    for (int n = 0; n < 4; ++n)
#pragma unroll
      for (int dc = 0; dc < 2; ++dc) {
        bf16x8 bk = *reinterpret_cast<const bf16x8*>(
            Ks + (n * 16 + lr) * 64 + (((dc * 4 + lg) ^ (lr & 7)) << 3));
        s[n] = __builtin_amdgcn_mfma_f32_16x16x32_bf16(aq[dc], bk, s[n], 0, 0, 0);
      }

    // scale + causal mask
    const bool needMask = (t * 64 + 63) > qrow;   // wave-uniform
#pragma unroll
    for (int n = 0; n < 4; ++n) {
      const int gcol = t * 64 + n * 16 + lr;
#pragma unroll
      for (int r = 0; r < 4; ++r) {
        float v = s[n][r] * 0.125f;
        if (needMask && gcol > qrow + lg * 4 + r) v = -1e30f;
        s[n][r] = v;
      }
    }
    // online softmax with defer-max (T13): row max over 16 lanes
    float pm[4];
#pragma unroll
    for (int r = 0; r < 4; ++r) {
      pm[r] = fmaxf(fmaxf(s[0][r], s[1][r]), fmaxf(s[2][r], s[3][r]));
#pragma unroll
      for (int off = 1; off < 16; off <<= 1)
        pm[r] = fmaxf(pm[r], __shfl_xor(pm[r], off));
    }
    bool need = (pm[0] > mr[0] + 8.f) | (pm[1] > mr[1] + 8.f) |
                (pm[2] > mr[2] + 8.f) | (pm[3] > mr[3] + 8.f);
    if (__any(need)) {
#pragma unroll
      for (int r = 0; r < 4; ++r) {
        float mn = fmaxf(mr[r], pm[r]);
        float al = __expf(mr[r] - mn);
        mr[r] = mn;
        ls[r] *= al;
#pragma unroll
        for (int dn = 0; dn < 4; ++dn) accO[dn][r] *= al;
      }
    }
    // P = exp(S-m) -> per-wave LDS (swizzled)
#pragma unroll
    for (int n = 0; n < 4; ++n)
#pragma unroll
      for (int r = 0; r < 4; ++r) {
        float p = __expf(s[n][r] - mr[r]);
        ls[r] += p;
        int row = lg * 4 + r, col = n * 16 + lr;
        PsW[row * 64 + ((((col >> 3) ^ (row & 7)) << 3) | (col & 7))] = f2bf(p);
      }
    asm volatile("s_waitcnt lgkmcnt(0)" ::: "memory");  // own-wave P writes done
    __builtin_amdgcn_sched_barrier(0);

    // O += P V
#pragma unroll
    for (int kk = 0; kk < 2; ++kk) {
      bf16x8 ap = *reinterpret_cast<const bf16x8*>(
          PsW + lr * 64 + (((kk * 4 + lg) ^ (lr & 7)) << 3));
#pragma unroll
      for (int dn = 0; dn < 4; ++dn) {
        int d = dn * 16 + lr;
        int swz = (d ^ (d >> 3)) & 7;
        bf16x8 bv = *reinterpret_cast<const bf16x8*>(
            Vt + d * 64 + (((kk * 4 + lg) ^ swz) << 3));
        accO[dn] = __builtin_amdgcn_mfma_f32_16x16x32_bf16(ap, bv, accO[dn], 0, 0, 0);
      }
    }
  } // t

#pragma unroll
  for (int r = 0; r < 4; ++r) {
#pragma unroll
    for (int off = 1; off < 16; off <<= 1)
      ls[r] += __shfl_xor(ls[r], off);
    ls[r] = 1.f / ls[r];
  }
#pragma unroll
  for (int dn = 0; dn < 4; ++dn)
#pragma unroll
    for (int r = 0; r < 4; ++r) {
      int row = qrow + lg * 4 + r;
      int col = h * 64 + dn * 16 + lr;
      o[(size_t)(b * T + row) * 1024 + col] = f2bf(accO[dn][r] * ls[r]);
    }
}

extern "C" void kernel_launch(void* const* d_in, const int* in_sizes, int n_in,
                              void* d_out, int out_size, void* d_ws, size_t ws_size,
                              hipStream_t stream) {
  const float* x     = (const float*)d_in[0];   // [2,2048,1024]
  const float* w_qkv = (const float*)d_in[1];   // [3072,1024]
  const float* w_out = (const float*)d_in[2];   // [1024,1024]
  float* out = (float*)d_out;                   // [2,2048,1024] fp32

  unsigned short* xb    = (unsigned short*)d_ws;                  // 4096*1024
  unsigned short* wqkvb = xb    + (size_t)4096 * 1024;            // 3072*1024
  unsigned short* woutb = wqkvb + (size_t)3072 * 1024;            // 1024*1024
  unsigned short* qkv   = woutb + (size_t)1024 * 1024;            // 4096*3072
  unsigned short* attn  = qkv   + (size_t)4096 * 3072;            // 4096*1024

  cast_kernel<<<dim3(4096), 256, 0, stream>>>(x,     xb,    4096 * 1024 / 4);
  cast_kernel<<<dim3(3072), 256, 0, stream>>>(w_qkv, wqkvb, 3072 * 1024 / 4);
  cast_kernel<<<dim3(1024), 256, 0, stream>>>(w_out, woutb, 1024 * 1024 / 4);

  gemm_bt<true ><<<dim3(32, 24), 256, 0, stream>>>(xb,   wqkvb, (void*)qkv,  4096, 3072, 1024);
  attn_kernel  <<<dim3(512), 512, 0, stream>>>(qkv, attn);
  gemm_bt<false><<<dim3(32,  8), 256, 0, stream>>>(attn, woutb, (void*)out, 4096, 1024, 1024);
}